// Round 1
// baseline (123.820 us; speedup 1.0000x reference)
//
#include <hip/hip_runtime.h>

typedef _Float16 f16;
typedef _Float16 f16x8 __attribute__((ext_vector_type(8)));
typedef float f32x4 __attribute__((ext_vector_type(4)));

__device__ __forceinline__ f32x4 mfma16(f16x8 a, f16x8 b, f32x4 c) {
    return __builtin_amdgcn_mfma_f32_16x16x32_f16(a, b, c, 0, 0, 0);
}

// ---- weight transpose + f16 cast: in [512][C] f32 -> out [C][512] f16 ----
__global__ __launch_bounds__(256) void k_wtrans(const float* __restrict__ in,
                                                f16* __restrict__ out, int C) {
    int idx = blockIdx.x * 256 + threadIdx.x;
    if (idx >= C * 512) return;
    int c = idx >> 9;   // output row 0..C-1
    int r = idx & 511;  // output col = input row
    out[idx] = (f16)in[(size_t)r * C + c];
}

// ---- LayerNorm: x [8192][512] f32 -> h [8192][512] f16 (1 wave/row) ----
__global__ __launch_bounds__(256) void k_ln(const float* __restrict__ x,
                                            const float* __restrict__ gamma,
                                            const float* __restrict__ beta,
                                            f16* __restrict__ h) {
    int row = blockIdx.x * 4 + (threadIdx.x >> 6);
    int lane = threadIdx.x & 63;
    const float* xr = x + (size_t)row * 512;
    float4 a = ((const float4*)xr)[lane * 2];
    float4 b = ((const float4*)xr)[lane * 2 + 1];
    float v[8] = {a.x, a.y, a.z, a.w, b.x, b.y, b.z, b.w};
    float s = 0.f, s2 = 0.f;
#pragma unroll
    for (int j = 0; j < 8; ++j) { s += v[j]; s2 += v[j] * v[j]; }
#pragma unroll
    for (int off = 1; off < 64; off <<= 1) {
        s  += __shfl_xor(s, off);
        s2 += __shfl_xor(s2, off);
    }
    float mu  = s * (1.f / 512.f);
    float var = s2 * (1.f / 512.f) - mu * mu;
    float rstd = rsqrtf(var + 1e-5f);
    float4 g0 = ((const float4*)gamma)[lane * 2];
    float4 g1 = ((const float4*)gamma)[lane * 2 + 1];
    float4 b0 = ((const float4*)beta)[lane * 2];
    float4 b1 = ((const float4*)beta)[lane * 2 + 1];
    float g[8]  = {g0.x, g0.y, g0.z, g0.w, g1.x, g1.y, g1.z, g1.w};
    float bb[8] = {b0.x, b0.y, b0.z, b0.w, b1.x, b1.y, b1.z, b1.w};
    f16x8 o;
#pragma unroll
    for (int j = 0; j < 8; ++j) o[j] = (f16)((v[j] - mu) * rstd * g[j] + bb[j]);
    *(f16x8*)&h[(size_t)row * 512 + lane * 8] = o;
}

// ---- QKV GEMM: h[8192][512] @ wqkvT[1536][512]^T -> q,k (B,H,N,D) + v^T (B,H,D,N), all f16
__global__ __launch_bounds__(256) void k_gemm_qkv(
    const f16* __restrict__ A, const f16* __restrict__ Bt,
    f16* __restrict__ q, f16* __restrict__ kmat, f16* __restrict__ vt)
{
    __shared__ f16 As[128][72];
    __shared__ f16 Bs[128][72];
    int tid = threadIdx.x;
    int wid = tid >> 6, lane = tid & 63;
    int wm = wid >> 1, wn = wid & 1;
    int l15 = lane & 15, l4 = lane >> 4;
    int rowBase = blockIdx.y * 128;
    int colBase = blockIdx.x * 128;
    f32x4 acc[4][4] = {};
    for (int kt = 0; kt < 512; kt += 64) {
#pragma unroll
        for (int i = 0; i < 4; ++i) {
            int c = tid + i * 256;
            int r = c >> 3, col = (c & 7) * 8;
            *(f16x8*)&As[r][col] = *(const f16x8*)&A [(size_t)(rowBase + r) * 512 + kt + col];
            *(f16x8*)&Bs[r][col] = *(const f16x8*)&Bt[(size_t)(colBase + r) * 512 + kt + col];
        }
        __syncthreads();
#pragma unroll
        for (int kk = 0; kk < 2; ++kk) {
            f16x8 af[4], bf[4];
#pragma unroll
            for (int m = 0; m < 4; ++m) af[m] = *(const f16x8*)&As[wm * 64 + m * 16 + l15][kk * 32 + l4 * 8];
#pragma unroll
            for (int n = 0; n < 4; ++n) bf[n] = *(const f16x8*)&Bs[wn * 64 + n * 16 + l15][kk * 32 + l4 * 8];
#pragma unroll
            for (int m = 0; m < 4; ++m)
#pragma unroll
                for (int n = 0; n < 4; ++n)
                    acc[m][n] = mfma16(af[m], bf[n], acc[m][n]);
        }
        __syncthreads();
    }
#pragma unroll
    for (int m = 0; m < 4; ++m)
#pragma unroll
        for (int n = 0; n < 4; ++n)
#pragma unroll
            for (int r = 0; r < 4; ++r) {
                int row = rowBase + wm * 64 + m * 16 + l4 * 4 + r;
                int col = colBase + wn * 64 + n * 16 + l15;
                f16 hv = (f16)acc[m][n][r];
                int b = row >> 10, nt = row & 1023;
                int which = col >> 9, hh = (col >> 6) & 7, d = col & 63;
                size_t hidx = ((size_t)(b * 8 + hh) * 1024 + nt) * 64 + d;
                if (which == 0)      q[hidx] = hv;
                else if (which == 1) kmat[hidx] = hv;
                else                 vt[((size_t)(b * 8 + hh) * 64 + d) * 1024 + nt] = hv;
            }
}

// ---- masked flash attention: per-block (qb, h, b); 4 waves x 32 q-rows ----
__global__ __launch_bounds__(256) void k_attn(
    const f16* __restrict__ q, const f16* __restrict__ kmat,
    const f16* __restrict__ vt, const int* __restrict__ mlab,
    f16* __restrict__ ao)
{
    __shared__ f16 Ks[128][72];
    __shared__ f16 Vs[64][136];
    __shared__ f16 Ps[4][32][136];
    int qb = blockIdx.x, hh = blockIdx.y, b = blockIdx.z;
    int tid = threadIdx.x, wid = tid >> 6, lane = tid & 63;
    int l15 = lane & 15, l4 = lane >> 4;
    int qbase = qb * 128;
    size_t bh = (size_t)(b * 8 + hh);

    if (mlab[b * 4 + (qb >> 1)] == 0) {
        // whole q-block is in a missing segment -> rows are exactly 0
        f16x8 z = {};
        for (int i = tid; i < 1024; i += 256) {
            int r = i >> 3, c = (i & 7) * 8;
            *(f16x8*)&ao[(size_t)(b * 1024 + qbase + r) * 512 + hh * 64 + c] = z;
        }
        return;
    }

    f16x8 qf[2][2];
#pragma unroll
    for (int m = 0; m < 2; ++m)
#pragma unroll
        for (int kk = 0; kk < 2; ++kk)
            qf[m][kk] = *(const f16x8*)&q[(bh * 1024 + qbase + wid * 32 + m * 16 + l15) * 64 + kk * 32 + l4 * 8];

    float mrun[2][4], lrun[2][4];
    f32x4 o[2][4] = {};
#pragma unroll
    for (int m = 0; m < 2; ++m)
#pragma unroll
        for (int r = 0; r < 4; ++r) { mrun[m][r] = -1e30f; lrun[m][r] = 0.f; }

#pragma unroll 1
    for (int s = 0; s < 4; ++s) {
        if (mlab[b * 4 + s] == 0) continue;  // block-uniform skip
#pragma unroll 1
        for (int ch = 0; ch < 2; ++ch) {
            int t0 = s * 256 + ch * 128;
            for (int i = tid; i < 1024; i += 256) {           // K tile: 128 tok x 64 d
                int r = i >> 3, c = (i & 7) * 8;
                *(f16x8*)&Ks[r][c] = *(const f16x8*)&kmat[(bh * 1024 + t0 + r) * 64 + c];
            }
            for (int i = tid; i < 1024; i += 256) {           // V^T tile: 64 d x 128 tok
                int r = i >> 4, c = (i & 15) * 8;
                *(f16x8*)&Vs[r][c] = *(const f16x8*)&vt[(bh * 64 + r) * 1024 + t0 + c];
            }
            __syncthreads();

            f32x4 sacc[2][8] = {};
#pragma unroll
            for (int kk = 0; kk < 2; ++kk) {
                f16x8 bf[8];
#pragma unroll
                for (int n = 0; n < 8; ++n) bf[n] = *(const f16x8*)&Ks[n * 16 + l15][kk * 32 + l4 * 8];
#pragma unroll
                for (int m = 0; m < 2; ++m)
#pragma unroll
                    for (int n = 0; n < 8; ++n)
                        sacc[m][n] = mfma16(qf[m][kk], bf[n], sacc[m][n]);
            }
#pragma unroll
            for (int m = 0; m < 2; ++m)
#pragma unroll
                for (int n = 0; n < 8; ++n) sacc[m][n] *= 0.125f;  // SCALE

            // online softmax (rows live in 16-lane groups: row = l4*4+r)
#pragma unroll
            for (int m = 0; m < 2; ++m)
#pragma unroll
                for (int r = 0; r < 4; ++r) {
                    float mx = sacc[m][0][r];
#pragma unroll
                    for (int n = 1; n < 8; ++n) mx = fmaxf(mx, sacc[m][n][r]);
#pragma unroll
                    for (int off = 1; off < 16; off <<= 1) mx = fmaxf(mx, __shfl_xor(mx, off));
                    float mnew = fmaxf(mrun[m][r], mx);
                    float alpha = __expf(mrun[m][r] - mnew);
                    mrun[m][r] = mnew;
#pragma unroll
                    for (int n = 0; n < 4; ++n) o[m][n][r] *= alpha;
                    float rs = 0.f;
#pragma unroll
                    for (int n = 0; n < 8; ++n) {
                        float p = __expf(sacc[m][n][r] - mnew);
                        sacc[m][n][r] = p;
                        rs += p;
                    }
#pragma unroll
                    for (int off = 1; off < 16; off <<= 1) rs += __shfl_xor(rs, off);
                    lrun[m][r] = lrun[m][r] * alpha + rs;
                }

            // P (C-layout) -> LDS -> A-layout fragments
#pragma unroll
            for (int m = 0; m < 2; ++m)
#pragma unroll
                for (int n = 0; n < 8; ++n)
#pragma unroll
                    for (int r = 0; r < 4; ++r)
                        Ps[wid][m * 16 + l4 * 4 + r][n * 16 + l15] = (f16)sacc[m][n][r];
            __syncthreads();

#pragma unroll
            for (int ks = 0; ks < 4; ++ks) {
                f16x8 pa[2], vb[4];
#pragma unroll
                for (int m = 0; m < 2; ++m) pa[m] = *(const f16x8*)&Ps[wid][m * 16 + l15][ks * 32 + l4 * 8];
#pragma unroll
                for (int n = 0; n < 4; ++n) vb[n] = *(const f16x8*)&Vs[n * 16 + l15][ks * 32 + l4 * 8];
#pragma unroll
                for (int m = 0; m < 2; ++m)
#pragma unroll
                    for (int n = 0; n < 4; ++n)
                        o[m][n] = mfma16(pa[m], vb[n], o[m][n]);
            }
            __syncthreads();
        }
    }

#pragma unroll
    for (int m = 0; m < 2; ++m)
#pragma unroll
        for (int n = 0; n < 4; ++n)
#pragma unroll
            for (int r = 0; r < 4; ++r) {
                float val = o[m][n][r] / lrun[m][r];
                ao[(size_t)(b * 1024 + qbase + wid * 32 + m * 16 + l4 * 4 + r) * 512 + hh * 64 + n * 16 + l15] = (f16)val;
            }
}

// ---- out GEMM: ao[8192][512] @ woutT[512][512]^T + b_out -> out f32 ----
__global__ __launch_bounds__(256) void k_gemm_out(
    const f16* __restrict__ A, const f16* __restrict__ Bt,
    const float* __restrict__ bias, float* __restrict__ out)
{
    __shared__ f16 As[128][72];
    __shared__ f16 Bs[128][72];
    int tid = threadIdx.x;
    int wid = tid >> 6, lane = tid & 63;
    int wm = wid >> 1, wn = wid & 1;
    int l15 = lane & 15, l4 = lane >> 4;
    int rowBase = blockIdx.y * 128;
    int colBase = blockIdx.x * 128;
    f32x4 acc[4][4] = {};
    for (int kt = 0; kt < 512; kt += 64) {
#pragma unroll
        for (int i = 0; i < 4; ++i) {
            int c = tid + i * 256;
            int r = c >> 3, col = (c & 7) * 8;
            *(f16x8*)&As[r][col] = *(const f16x8*)&A [(size_t)(rowBase + r) * 512 + kt + col];
            *(f16x8*)&Bs[r][col] = *(const f16x8*)&Bt[(size_t)(colBase + r) * 512 + kt + col];
        }
        __syncthreads();
#pragma unroll
        for (int kk = 0; kk < 2; ++kk) {
            f16x8 af[4], bf[4];
#pragma unroll
            for (int m = 0; m < 4; ++m) af[m] = *(const f16x8*)&As[wm * 64 + m * 16 + l15][kk * 32 + l4 * 8];
#pragma unroll
            for (int n = 0; n < 4; ++n) bf[n] = *(const f16x8*)&Bs[wn * 64 + n * 16 + l15][kk * 32 + l4 * 8];
#pragma unroll
            for (int m = 0; m < 4; ++m)
#pragma unroll
                for (int n = 0; n < 4; ++n)
                    acc[m][n] = mfma16(af[m], bf[n], acc[m][n]);
        }
        __syncthreads();
    }
#pragma unroll
    for (int m = 0; m < 4; ++m)
#pragma unroll
        for (int n = 0; n < 4; ++n)
#pragma unroll
            for (int r = 0; r < 4; ++r) {
                int row = rowBase + wm * 64 + m * 16 + l4 * 4 + r;
                int col = colBase + wn * 64 + n * 16 + l15;
                out[(size_t)row * 512 + col] = acc[m][n][r] + bias[col];
            }
}

extern "C" void kernel_launch(void* const* d_in, const int* in_sizes, int n_in,
                              void* d_out, int out_size, void* d_ws, size_t ws_size,
                              hipStream_t stream) {
    const float* x     = (const float*)d_in[0];
    const int*   mlab  = (const int*)d_in[1];
    const float* gamma = (const float*)d_in[2];
    const float* beta  = (const float*)d_in[3];
    const float* wqkv  = (const float*)d_in[4];
    const float* wout  = (const float*)d_in[5];
    const float* bout  = (const float*)d_in[6];
    float* out = (float*)d_out;

    f16* h     = (f16*)d_ws;                 // 8192*512
    f16* wqkvT = h + 8192 * 512;             // 1536*512
    f16* woutT = wqkvT + 1536 * 512;         // 512*512
    f16* q     = woutT + 512 * 512;          // 8*8*1024*64
    f16* kmat  = q + 4 * 1024 * 1024;
    f16* vt    = kmat + 4 * 1024 * 1024;
    f16* ao    = h;                          // h dead after QKV GEMM -> reuse

    k_wtrans<<<(1536 * 512 + 255) / 256, 256, 0, stream>>>(wqkv, wqkvT, 1536);
    k_wtrans<<<(512 * 512 + 255) / 256, 256, 0, stream>>>(wout, woutT, 512);
    k_ln<<<2048, 256, 0, stream>>>(x, gamma, beta, h);
    k_gemm_qkv<<<dim3(12, 64), 256, 0, stream>>>(h, wqkvT, q, kmat, vt);
    k_attn<<<dim3(8, 8, 8), 256, 0, stream>>>(q, kmat, vt, mlab, ao);
    k_gemm_out<<<dim3(4, 64), 256, 0, stream>>>(ao, woutT, bout, out);
}

// Round 2
// 107.403 us; speedup vs baseline: 1.1529x; 1.1529x over previous
//
#include <hip/hip_runtime.h>

typedef _Float16 f16;
typedef _Float16 f16x8 __attribute__((ext_vector_type(8)));
typedef float f32x4 __attribute__((ext_vector_type(4)));

typedef __attribute__((address_space(1))) void gvoid;
typedef __attribute__((address_space(3))) void lvoid;
#define GLD16(gp, lp) __builtin_amdgcn_global_load_lds((gvoid*)(gp), (lvoid*)(lp), 16, 0, 0)

__device__ __forceinline__ f32x4 mfma16(f16x8 a, f16x8 b, f32x4 c) {
    return __builtin_amdgcn_mfma_f32_16x16x32_f16(a, b, c, 0, 0, 0);
}

// ---- weight transpose + f16 cast: in [512][C] f32 -> out [C][512] f16 (LDS tile) ----
__global__ __launch_bounds__(256) void k_wtrans(const float* __restrict__ in,
                                                f16* __restrict__ out, int C) {
    __shared__ float t[64][65];
    int tid = threadIdx.x;
    int c0 = blockIdx.x * 64, r0 = blockIdx.y * 64;
#pragma unroll
    for (int i = 0; i < 16; ++i) {
        int r = i * 4 + (tid >> 6), c = tid & 63;
        t[r][c] = in[(size_t)(r0 + r) * C + c0 + c];
    }
    __syncthreads();
#pragma unroll
    for (int i = 0; i < 16; ++i) {
        int cr = i * 4 + (tid >> 6), cc = tid & 63;
        out[(size_t)(c0 + cr) * 512 + r0 + cc] = (f16)t[cc][cr];
    }
}

// ---- LayerNorm: x [8192][512] f32 -> h [8192][512] f16 (1 wave/row) ----
__global__ __launch_bounds__(256) void k_ln(const float* __restrict__ x,
                                            const float* __restrict__ gamma,
                                            const float* __restrict__ beta,
                                            f16* __restrict__ h) {
    int row = blockIdx.x * 4 + (threadIdx.x >> 6);
    int lane = threadIdx.x & 63;
    const float* xr = x + (size_t)row * 512;
    float4 a = ((const float4*)xr)[lane * 2];
    float4 b = ((const float4*)xr)[lane * 2 + 1];
    float v[8] = {a.x, a.y, a.z, a.w, b.x, b.y, b.z, b.w};
    float s = 0.f, s2 = 0.f;
#pragma unroll
    for (int j = 0; j < 8; ++j) { s += v[j]; s2 += v[j] * v[j]; }
#pragma unroll
    for (int off = 1; off < 64; off <<= 1) {
        s  += __shfl_xor(s, off);
        s2 += __shfl_xor(s2, off);
    }
    float mu  = s * (1.f / 512.f);
    float var = s2 * (1.f / 512.f) - mu * mu;
    float rstd = rsqrtf(var + 1e-5f);
    float4 g0 = ((const float4*)gamma)[lane * 2];
    float4 g1 = ((const float4*)gamma)[lane * 2 + 1];
    float4 b0 = ((const float4*)beta)[lane * 2];
    float4 b1 = ((const float4*)beta)[lane * 2 + 1];
    float g[8]  = {g0.x, g0.y, g0.z, g0.w, g1.x, g1.y, g1.z, g1.w};
    float bb[8] = {b0.x, b0.y, b0.z, b0.w, b1.x, b1.y, b1.z, b1.w};
    f16x8 o;
#pragma unroll
    for (int j = 0; j < 8; ++j) o[j] = (f16)((v[j] - mu) * rstd * g[j] + bb[j]);
    *(f16x8*)&h[(size_t)row * 512 + lane * 8] = o;
}

// ---- QKV GEMM (128x128 tile, BK=64, global_load_lds, seg-skip) ----
__global__ __launch_bounds__(256) void k_gemm_qkv(
    const f16* __restrict__ A, const f16* __restrict__ Bt, const int* __restrict__ mlab,
    f16* __restrict__ q, f16* __restrict__ kmat, f16* __restrict__ vt)
{
    __shared__ f16 As[128 * 64];
    __shared__ f16 Bs[128 * 64];
    int tid = threadIdx.x, wid = tid >> 6, lane = tid & 63;
    int wm = wid >> 1, wn = wid & 1;
    int l15 = lane & 15, l4 = lane >> 4;
    int rowBase = blockIdx.y * 128;
    int colBase = blockIdx.x * 128;
    // q/k/v of missing segments are never read downstream -> skip tile
    int bb = rowBase >> 10, seg = (rowBase & 1023) >> 8;
    if (mlab[bb * 4 + seg] == 0) return;

    int srow = lane >> 3;          // row within 8-row group
    int scol = (lane & 7) * 8;     // f16 col within 64
    f32x4 acc[4][4] = {};
    for (int kt = 0; kt < 512; kt += 64) {
#pragma unroll
        for (int i = 0; i < 4; ++i) {
            int rg = (wid * 4 + i) * 8;
            GLD16(&A [(size_t)(rowBase + rg + srow) * 512 + kt + scol], &As[rg * 64]);
            GLD16(&Bt[(size_t)(colBase + rg + srow) * 512 + kt + scol], &Bs[rg * 64]);
        }
        __syncthreads();
#pragma unroll
        for (int kk = 0; kk < 2; ++kk) {
            f16x8 af[4], bf[4];
#pragma unroll
            for (int m = 0; m < 4; ++m) af[m] = *(const f16x8*)&As[(wm * 64 + m * 16 + l15) * 64 + kk * 32 + l4 * 8];
#pragma unroll
            for (int n = 0; n < 4; ++n) bf[n] = *(const f16x8*)&Bs[(wn * 64 + n * 16 + l15) * 64 + kk * 32 + l4 * 8];
#pragma unroll
            for (int m = 0; m < 4; ++m)
#pragma unroll
                for (int n = 0; n < 4; ++n)
                    acc[m][n] = mfma16(af[m], bf[n], acc[m][n]);
        }
        __syncthreads();
    }
#pragma unroll
    for (int m = 0; m < 4; ++m)
#pragma unroll
        for (int n = 0; n < 4; ++n)
#pragma unroll
            for (int r = 0; r < 4; ++r) {
                int row = rowBase + wm * 64 + m * 16 + l4 * 4 + r;
                int col = colBase + wn * 64 + n * 16 + l15;
                f16 hv = (f16)acc[m][n][r];
                int b = row >> 10, nt = row & 1023;
                int which = col >> 9, hh = (col >> 6) & 7, d = col & 63;
                size_t hidx = ((size_t)(b * 8 + hh) * 1024 + nt) * 64 + d;
                if (which == 0)      q[hidx] = hv;
                else if (which == 1) kmat[hidx] = hv;
                else                 vt[((size_t)(b * 8 + hh) * 64 + d) * 1024 + nt] = hv;
            }
}

// ---- masked flash attention v2: swapped-QK lane-local softmax, T14 prefetch ----
// grid (16,8,8): 64 q-rows/block, 4 waves x 16 rows
__global__ __launch_bounds__(256, 4) void k_attn(
    const f16* __restrict__ q, const f16* __restrict__ kmat,
    const f16* __restrict__ vt, const int* __restrict__ mlab,
    f16* __restrict__ ao)
{
    __shared__ f16 Ks[128][72];
    __shared__ f16 Vs[64][136];
    int qb = blockIdx.x, hh = blockIdx.y, b = blockIdx.z;
    int tid = threadIdx.x, wid = tid >> 6, lane = tid & 63;
    int l15 = lane & 15, l4 = lane >> 4;
    int qbase = qb * 64;
    size_t bh = (size_t)(b * 8 + hh);

    if (mlab[b * 4 + (qb >> 2)] == 0) {     // missing q-segment -> exact zeros
        f16x8 z = {};
#pragma unroll
        for (int i = 0; i < 2; ++i) {
            int idx = tid + i * 256;
            *(f16x8*)&ao[(size_t)(b * 1024 + qbase + (idx >> 3)) * 512 + hh * 64 + (idx & 7) * 8] = z;
        }
        return;
    }

    // present 128-token chunks, packed 4 bits each (value = t0/128)
    unsigned chpack = 0; int nch = 0;
#pragma unroll
    for (int s = 0; s < 4; ++s)
        if (mlab[b * 4 + s] != 0) {
            chpack |= (unsigned)(2 * s)     << (4 * nch); ++nch;
            chpack |= (unsigned)(2 * s + 1) << (4 * nch); ++nch;
        }

    // Q fragment (B-operand rows = this wave's 16 q rows), pre-scaled by 1/8
    f16x8 qf[2];
#pragma unroll
    for (int kk = 0; kk < 2; ++kk) {
        qf[kk] = *(const f16x8*)&q[(bh * 1024 + qbase + wid * 16 + l15) * 64 + kk * 32 + l4 * 8];
#pragma unroll
        for (int j = 0; j < 8; ++j) qf[kk][j] = qf[kk][j] * (f16)0.125;
    }

    float mrun = -1e30f, lrun = 0.f;
    f32x4 o[4] = {};
    int4 kreg[4], vreg[4];

    // prologue: stage chunk 0
    {
        int t0 = (int)(chpack & 15) << 7;
#pragma unroll
        for (int i = 0; i < 4; ++i) {
            int idx = tid + i * 256;
            kreg[i] = *(const int4*)&kmat[(bh * 1024 + t0 + (idx >> 3)) * 64 + (idx & 7) * 8];
            vreg[i] = *(const int4*)&vt[(bh * 64 + (idx >> 4)) * 1024 + t0 + (idx & 15) * 8];
        }
#pragma unroll
        for (int i = 0; i < 4; ++i) {
            int idx = tid + i * 256;
            *(int4*)&Ks[idx >> 3][(idx & 7) * 8] = kreg[i];
            *(int4*)&Vs[idx >> 4][(idx & 15) * 8] = vreg[i];
        }
    }

    for (int c = 0; c < nch; ++c) {
        __syncthreads();                       // LDS chunk c ready
        bool more = (c + 1 < nch);
        if (more) {                            // T14: issue next-chunk loads early
            int t0 = (int)((chpack >> (4 * (c + 1))) & 15) << 7;
#pragma unroll
            for (int i = 0; i < 4; ++i) {
                int idx = tid + i * 256;
                kreg[i] = *(const int4*)&kmat[(bh * 1024 + t0 + (idx >> 3)) * 64 + (idx & 7) * 8];
                vreg[i] = *(const int4*)&vt[(bh * 64 + (idx >> 4)) * 1024 + t0 + (idx & 15) * 8];
            }
        }

        // QK^T swapped: st[n] holds S^T, row k=n*16+l4*4+r, col q=l15 (lane-local row!)
        f32x4 st[8] = {};
#pragma unroll
        for (int kk = 0; kk < 2; ++kk)
#pragma unroll
            for (int n = 0; n < 8; ++n) {
                f16x8 ka = *(const f16x8*)&Ks[n * 16 + l15][kk * 32 + l4 * 8];
                st[n] = mfma16(ka, qf[kk], st[n]);
            }

        // lane-local online softmax over this lane's 32 k-values
        f32x4 m4 = st[0];
#pragma unroll
        for (int n = 1; n < 8; ++n)
#pragma unroll
            for (int r = 0; r < 4; ++r) m4[r] = fmaxf(m4[r], st[n][r]);
        float mx = fmaxf(fmaxf(m4[0], m4[1]), fmaxf(m4[2], m4[3]));
        mx = fmaxf(mx, __shfl_xor(mx, 16));
        mx = fmaxf(mx, __shfl_xor(mx, 32));
        float mnew = fmaxf(mrun, mx);
        float alpha = __expf(mrun - mnew);
        mrun = mnew;
        float rs = 0.f;
        union PK { f16 h[4]; long long ll; } pk[8];
#pragma unroll
        for (int n = 0; n < 8; ++n)
#pragma unroll
            for (int r = 0; r < 4; ++r) {
                float p = __expf(st[n][r] - mnew);
                rs += p;
                pk[n].h[r] = (f16)p;
            }
        rs += __shfl_xor(rs, 16);
        rs += __shfl_xor(rs, 32);
        lrun = lrun * alpha + rs;
#pragma unroll
        for (int nd = 0; nd < 4; ++nd) o[nd] *= alpha;

        // redistribute P among 4-lane group (l15 fixed): target needs k=ks*32+l4*8+j
        int srcA = l15 + ((l4 & 1) * 2) * 16;
        int srcB = srcA + 16;
        int sel = l4 >> 1;
#pragma unroll
        for (int ks = 0; ks < 4; ++ks) {
            long long A0 = __shfl(pk[ks * 2].ll,     srcA);
            long long A1 = __shfl(pk[ks * 2 + 1].ll, srcA);
            long long B0 = __shfl(pk[ks * 2].ll,     srcB);
            long long B1 = __shfl(pk[ks * 2 + 1].ll, srcB);
            union PB { long long ll[2]; f16x8 v; } pb;
            pb.ll[0] = sel ? A1 : A0;
            pb.ll[1] = sel ? B1 : B0;
#pragma unroll
            for (int nd = 0; nd < 4; ++nd) {       // PV swapped: O^T[d][q], col q=l15
                f16x8 va = *(const f16x8*)&Vs[nd * 16 + l15][ks * 32 + l4 * 8];
                o[nd] = mfma16(va, pb.v, o[nd]);
            }
        }
        __syncthreads();                            // all waves done reading LDS
        if (more) {                                 // write prefetched chunk
#pragma unroll
            for (int i = 0; i < 4; ++i) {
                int idx = tid + i * 256;
                *(int4*)&Ks[idx >> 3][(idx & 7) * 8] = kreg[i];
                *(int4*)&Vs[idx >> 4][(idx & 15) * 8] = vreg[i];
            }
        }
    }

    float inv = 1.f / lrun;
    int qrow = qbase + wid * 16 + l15;
#pragma unroll
    for (int nd = 0; nd < 4; ++nd) {
        union { f16 h[4]; long long ll; } w;
#pragma unroll
        for (int r = 0; r < 4; ++r) w.h[r] = (f16)(o[nd][r] * inv);
        *(long long*)&ao[(size_t)(b * 1024 + qrow) * 512 + hh * 64 + nd * 16 + l4 * 4] = w.ll;
    }
}

// ---- out GEMM (64x128 tile, BK=64, global_load_lds, bias-fill for zero rows) ----
__global__ __launch_bounds__(256) void k_gemm_out(
    const f16* __restrict__ A, const f16* __restrict__ Bt, const int* __restrict__ mlab,
    const float* __restrict__ bias, float* __restrict__ out)
{
    __shared__ f16 As[64 * 64];
    __shared__ f16 Bs[128 * 64];
    int tid = threadIdx.x, wid = tid >> 6, lane = tid & 63;
    int wm = wid >> 1, wn = wid & 1;
    int l15 = lane & 15, l4 = lane >> 4;
    int rowBase = blockIdx.y * 64;
    int colBase = blockIdx.x * 128;
    int bb = rowBase >> 10, seg = (rowBase & 1023) >> 8;
    if (mlab[bb * 4 + seg] == 0) {      // ao rows are zero -> out = bias
        for (int i = tid; i < 64 * 128; i += 256)
            out[(size_t)(rowBase + (i >> 7)) * 512 + colBase + (i & 127)] = bias[colBase + (i & 127)];
        return;
    }

    int srow = lane >> 3, scol = (lane & 7) * 8;
    f32x4 acc[2][4] = {};
    for (int kt = 0; kt < 512; kt += 64) {
#pragma unroll
        for (int i = 0; i < 2; ++i) {
            int rg = (wid * 2 + i) * 8;
            GLD16(&A[(size_t)(rowBase + rg + srow) * 512 + kt + scol], &As[rg * 64]);
        }
#pragma unroll
        for (int i = 0; i < 4; ++i) {
            int rg = (wid * 4 + i) * 8;
            GLD16(&Bt[(size_t)(colBase + rg + srow) * 512 + kt + scol], &Bs[rg * 64]);
        }
        __syncthreads();
#pragma unroll
        for (int kk = 0; kk < 2; ++kk) {
            f16x8 af[2], bf[4];
#pragma unroll
            for (int m = 0; m < 2; ++m) af[m] = *(const f16x8*)&As[(wm * 32 + m * 16 + l15) * 64 + kk * 32 + l4 * 8];
#pragma unroll
            for (int n = 0; n < 4; ++n) bf[n] = *(const f16x8*)&Bs[(wn * 64 + n * 16 + l15) * 64 + kk * 32 + l4 * 8];
#pragma unroll
            for (int m = 0; m < 2; ++m)
#pragma unroll
                for (int n = 0; n < 4; ++n)
                    acc[m][n] = mfma16(af[m], bf[n], acc[m][n]);
        }
        __syncthreads();
    }
#pragma unroll
    for (int m = 0; m < 2; ++m)
#pragma unroll
        for (int n = 0; n < 4; ++n)
#pragma unroll
            for (int r = 0; r < 4; ++r) {
                int row = rowBase + wm * 32 + m * 16 + l4 * 4 + r;
                int col = colBase + wn * 64 + n * 16 + l15;
                out[(size_t)row * 512 + col] = acc[m][n][r] + bias[col];
            }
}

extern "C" void kernel_launch(void* const* d_in, const int* in_sizes, int n_in,
                              void* d_out, int out_size, void* d_ws, size_t ws_size,
                              hipStream_t stream) {
    const float* x     = (const float*)d_in[0];
    const int*   mlab  = (const int*)d_in[1];
    const float* gamma = (const float*)d_in[2];
    const float* beta  = (const float*)d_in[3];
    const float* wqkv  = (const float*)d_in[4];
    const float* wout  = (const float*)d_in[5];
    const float* bout  = (const float*)d_in[6];
    float* out = (float*)d_out;

    f16* h     = (f16*)d_ws;                 // 8192*512
    f16* wqkvT = h + 8192 * 512;             // 1536*512
    f16* woutT = wqkvT + 1536 * 512;         // 512*512
    f16* q     = woutT + 512 * 512;          // [B*H][1024][64]
    f16* kmat  = q + 4 * 1024 * 1024;
    f16* vt    = kmat + 4 * 1024 * 1024;     // [B*H][64][1024]
    f16* ao    = h;                          // h dead after QKV GEMM -> reuse

    k_wtrans<<<dim3(24, 8), 256, 0, stream>>>(wqkv, wqkvT, 1536);
    k_wtrans<<<dim3(8, 8), 256, 0, stream>>>(wout, woutT, 512);
    k_ln<<<2048, 256, 0, stream>>>(x, gamma, beta, h);
    k_gemm_qkv<<<dim3(12, 64), 256, 0, stream>>>(h, wqkvT, mlab, q, kmat, vt);
    k_attn<<<dim3(16, 8, 8), 256, 0, stream>>>(q, kmat, vt, mlab, ao);
    k_gemm_out<<<dim3(4, 128), 256, 0, stream>>>(ao, woutT, mlab, bout, out);
}